// Round 4
// baseline (1563.907 us; speedup 1.0000x reference)
//
#include <hip/hip_runtime.h>

#define T_STEPS 2000
#define NBATCH  256
#define HID     51
#define NPAIR   26   // 52 k-slots (51 h1 + 1 h2) as 26 f16 pairs
#define FEAT    49

typedef _Float16 v2h __attribute__((ext_vector_type(2)));

__device__ __forceinline__ float rl(float v, int lane) {
    return __int_as_float(__builtin_amdgcn_readlane(__float_as_int(v), lane));
}
__device__ __forceinline__ int rli(int v, int lane) {
    return __builtin_amdgcn_readlane(v, lane);
}
__device__ __forceinline__ float sigmoidf_fast(float x) {
    return __builtin_amdgcn_rcpf(1.0f + __builtin_amdgcn_exp2f(-1.4426950408889634f * x));
}
__device__ __forceinline__ float tanhf_fast(float x) {
    return 1.0f - 2.0f * __builtin_amdgcn_rcpf(1.0f + __builtin_amdgcn_exp2f(2.8853900817779268f * x));
}
__device__ __forceinline__ int packh2(float lo, float hi) {
    v2h p = (v2h){(_Float16)lo, (_Float16)hi};
    return __builtin_bit_cast(int, p);
}
__device__ __forceinline__ float dot2(int w, int h, float acc) {
#if __has_builtin(__builtin_amdgcn_fdot2)
    return __builtin_amdgcn_fdot2(__builtin_bit_cast(v2h, w),
                                  __builtin_bit_cast(v2h, h), acc, false);
#else
    v2h a = __builtin_bit_cast(v2h, w), b = __builtin_bit_cast(v2h, h);
    return acc + (float)a.x * (float)b.x + (float)a.y * (float)b.y;
#endif
}

// Kernel 1: x_lin = relu(x @ Wl.T + bl) -> io (= d_out reused as scratch).
__global__ __launch_bounds__(256) void proj_kernel(const float* __restrict__ x,
                                                   const float* __restrict__ Wl,
                                                   const float* __restrict__ bl,
                                                   float* __restrict__ io) {
    __shared__ float tile[256 * FEAT];
    const int base = blockIdx.x * 256;
    const float4* src4 = (const float4*)(x + (size_t)base * FEAT);
    float4* t4 = (float4*)tile;
    for (int i = threadIdx.x; i < (256 * FEAT) / 4; i += 256) t4[i] = src4[i];
    __syncthreads();
    const float* row = &tile[threadIdx.x * FEAT];
    float acc = bl[0];
#pragma unroll
    for (int j = 0; j < FEAT; ++j) acc = fmaf(row[j], Wl[j], acc);
    io[base + threadIdx.x] = fmaxf(acc, 0.0f);
}

// Kernel 2: one wave per sample. Lane l<51 = LSTM1 row l (4 gates); lane 51 =
// LSTM2 (same matvec + same nonlinearity, one step skewed). Weights held as
// 104 packed-f16 VGPRs/lane (fp32 demand of 208 regs exceeded the 256
// architected-VGPR cap -> scratch; f16 fits with headroom). Matvec via
// v_dot2_f32_f16 (2 MAC/instr, f32 accumulate). h broadcast: f16-convert,
// 52 readlanes -> scalar pack into 26 uniform half2.
__global__ __attribute__((amdgpu_flat_work_group_size(64, 64), amdgpu_waves_per_eu(1)))
void rnn_kernel(
    float* io,
    const float* __restrict__ Wih1, const float* __restrict__ Whh1,
    const float* __restrict__ bih1, const float* __restrict__ bhh1,
    const float* __restrict__ Wih2, const float* __restrict__ Whh2,
    const float* __restrict__ bih2, const float* __restrict__ bhh2,
    const float* __restrict__ Wa, const float* __restrict__ ba)
{
    const int n    = blockIdx.x;
    const int lane = threadIdx.x;
    float* xptr = io + (size_t)n * T_STEPS;
    const int total = NBATCH * T_STEPS;

    // ---- one-time weight load -> packed f16 pairs (104 VGPRs/lane) ----
    int w0p[NPAIR], w1p[NPAIR], w2p[NPAIR], w3p[NPAIR];
    {
        const float *s0, *s1, *s2, *s3;
        float msk;
        if (lane < HID) {
            s0 = Whh1 + (0 * HID + lane) * HID;
            s1 = Whh1 + (1 * HID + lane) * HID;
            s2 = Whh1 + (2 * HID + lane) * HID;
            s3 = Whh1 + (3 * HID + lane) * HID;
            msk = 1.0f;
        } else {
            s0 = Wih2 + 0 * HID; s1 = Wih2 + 1 * HID;
            s2 = Wih2 + 2 * HID; s3 = Wih2 + 3 * HID;
            msk = (lane == HID) ? 1.0f : 0.0f;
        }
        const float m2 = (lane == HID) ? 1.0f : 0.0f;
        const float h2w0 = Whh2[0] * m2, h2w1 = Whh2[1] * m2;
        const float h2w2 = Whh2[2] * m2, h2w3 = Whh2[3] * m2;
#pragma unroll
        for (int j = 0; j < NPAIR; ++j) {
            const int k0 = 2 * j, k1 = 2 * j + 1;
            float hi0, hi1, hi2, hi3;
            if (k1 < HID) {
                hi0 = s0[k1] * msk; hi1 = s1[k1] * msk;
                hi2 = s2[k1] * msk; hi3 = s3[k1] * msk;
            } else {  // k1 == 51: the Whh2 column (nonzero only on lane 51)
                hi0 = h2w0; hi1 = h2w1; hi2 = h2w2; hi3 = h2w3;
            }
            int p0 = packh2(s0[k0] * msk, hi0);
            int p1 = packh2(s1[k0] * msk, hi1);
            int p2 = packh2(s2[k0] * msk, hi2);
            int p3 = packh2(s3[k0] * msk, hi3);
            asm("" : "+v"(p0), "+v"(p1), "+v"(p2), "+v"(p3));
            w0p[j] = p0; w1p[j] = p1; w2p[j] = p2; w3p[j] = p3;
        }
    }

    // per-lane x-weights and biases (fp32)
    float wx0 = 0.0f, wx1 = 0.0f, wx2 = 0.0f, wx3 = 0.0f;
    float b0 = 0.0f, b1 = 0.0f, b2 = 0.0f, b3 = 0.0f;
    if (lane < HID) {
        wx0 = Wih1[lane];           wx1 = Wih1[HID + lane];
        wx2 = Wih1[2 * HID + lane]; wx3 = Wih1[3 * HID + lane];
        b0 = bih1[lane] + bhh1[lane];
        b1 = bih1[HID + lane] + bhh1[HID + lane];
        b2 = bih1[2 * HID + lane] + bhh1[2 * HID + lane];
        b3 = bih1[3 * HID + lane] + bhh1[3 * HID + lane];
    } else if (lane == HID) {
        b0 = bih2[0] + bhh2[0]; b1 = bih2[1] + bhh2[1];
        b2 = bih2[2] + bhh2[2]; b3 = bih2[3] + bhh2[3];
    }
    const float wav = Wa[0], bav = ba[0];

    // broadcast state: 26 uniform half2 (SGPRs); pair 25 hi-slot = h2
    int sh2[NPAIR];
#pragma unroll
    for (int j = 0; j < NPAIR; ++j) sh2[j] = 0;

    float c = 0.0f, h = 0.0f;

    // x_lin chunk prefetch: 64 values per lane-chunk, double buffered
    float xa = xptr[lane];
    float xb = xptr[64 + lane];

#pragma unroll 1
    for (int t = 0; t <= T_STEPS; ++t) {
        if ((t & 63) == 0 && t > 0 && t < T_STEPS) {
            xa = xb;
            int bidx = n * T_STEPS + t + 64 + lane;
            bidx = bidx < total ? bidx : (total - 1);
            xb = io[bidx];
        }
        float xt = rl(xa, t & 63);

        // ---- matvec: 4 gate rows/lane, 26 dot2 each (f32 accumulate) ----
        float a0 = fmaf(wx0, xt, b0);
        float a1 = fmaf(wx1, xt, b1);
        float a2 = fmaf(wx2, xt, b2);
        float a3 = fmaf(wx3, xt, b3);
#pragma unroll
        for (int j = 0; j < NPAIR; ++j) {
            int hp = sh2[j];
            a0 = dot2(w0p[j], hp, a0);
            a1 = dot2(w1p[j], hp, a1);
            a2 = dot2(w2p[j], hp, a2);
            a3 = dot2(w3p[j], hp, a3);
        }

        // ---- shared nonlinearity + state update (lane51 = LSTM2) ----
        float ig = sigmoidf_fast(a0);
        float fg = sigmoidf_fast(a1);
        float gg = tanhf_fast(a2);
        float og = sigmoidf_fast(a3);
        c = fmaf(fg, c, ig * gg);
        h = og * tanhf_fast(c);
        if (t == 0 && lane >= HID) { c = 0.0f; h = 0.0f; }  // LSTM2 zero init (skewed)

        float outv = fmaf(h, wav, bav);
        if (t > 0 && lane == HID) xptr[t - 1] = outv;

        // ---- broadcast h as f16 pairs for next step ----
        int hz = (int)(unsigned)__builtin_bit_cast(unsigned short, (_Float16)h);
#pragma unroll
        for (int j = 0; j < NPAIR; ++j) {
            int lo = rli(hz, 2 * j);
            int hi = rli(hz, 2 * j + 1);
            sh2[j] = lo | (hi << 16);
        }
    }
}

extern "C" void kernel_launch(void* const* d_in, const int* in_sizes, int n_in,
                              void* d_out, int out_size, void* d_ws, size_t ws_size,
                              hipStream_t stream) {
    const float* x    = (const float*)d_in[0];
    const float* Wl   = (const float*)d_in[1];
    const float* bl   = (const float*)d_in[2];
    const float* Wih1 = (const float*)d_in[3];
    const float* Whh1 = (const float*)d_in[4];
    const float* bih1 = (const float*)d_in[5];
    const float* bhh1 = (const float*)d_in[6];
    const float* Wih2 = (const float*)d_in[7];
    const float* Whh2 = (const float*)d_in[8];
    const float* bih2 = (const float*)d_in[9];
    const float* bhh2 = (const float*)d_in[10];
    const float* Wa   = (const float*)d_in[11];
    const float* ba   = (const float*)d_in[12];
    float* io = (float*)d_out;

    proj_kernel<<<(NBATCH * T_STEPS) / 256, 256, 0, stream>>>(x, Wl, bl, io);
    rnn_kernel<<<NBATCH, 64, 0, stream>>>(io, Wih1, Whh1, bih1, bhh1,
                                          Wih2, Whh2, bih2, bhh2, Wa, ba);
}

// Round 5
// 1556.714 us; speedup vs baseline: 1.0046x; 1.0046x over previous
//
#include <hip/hip_runtime.h>

#define T_STEPS 2000
#define NBATCH  256
#define HID     51
#define FEAT    49
#define ROWF4   784        // 64 rows * 49 floats / 4 per chunk
#define XTOT4   (NBATCH * T_STEPS * FEAT / 4)

typedef _Float16 v2h __attribute__((ext_vector_type(2)));

__device__ __forceinline__ float rl(float v, int lane) {
    return __int_as_float(__builtin_amdgcn_readlane(__float_as_int(v), lane));
}
__device__ __forceinline__ int rli(int v, int lane) {
    return __builtin_amdgcn_readlane(v, lane);
}
__device__ __forceinline__ float sigmoidf_fast(float x) {
    return __builtin_amdgcn_rcpf(1.0f + __builtin_amdgcn_exp2f(-1.4426950408889634f * x));
}
__device__ __forceinline__ float tanhf_fast(float x) {
    return 1.0f - 2.0f * __builtin_amdgcn_rcpf(1.0f + __builtin_amdgcn_exp2f(2.8853900817779268f * x));
}
__device__ __forceinline__ int packh2(float lo, float hi) {
    v2h p = (v2h){(_Float16)lo, (_Float16)hi};
    return __builtin_bit_cast(int, p);
}
__device__ __forceinline__ float dot2(int w, int h, float acc) {
    return __builtin_amdgcn_fdot2(__builtin_bit_cast(v2h, w),
                                  __builtin_bit_cast(v2h, h), acc, false);
}
__device__ __forceinline__ float row_dot(const float* row, const float* __restrict__ Wl) {
    float a0 = 0, a1 = 0, a2 = 0, a3 = 0, a4 = 0, a5 = 0, a6 = 0;
#pragma unroll
    for (int j = 0; j < FEAT; j += 7) {
        a0 = fmaf(row[j    ], Wl[j    ], a0);
        a1 = fmaf(row[j + 1], Wl[j + 1], a1);
        a2 = fmaf(row[j + 2], Wl[j + 2], a2);
        a3 = fmaf(row[j + 3], Wl[j + 3], a3);
        a4 = fmaf(row[j + 4], Wl[j + 4], a4);
        a5 = fmaf(row[j + 5], Wl[j + 5], a5);
        a6 = fmaf(row[j + 6], Wl[j + 6], a6);
    }
    return ((a0 + a1) + (a2 + a3)) + ((a4 + a5) + a6);
}

#define REP13(F) F(0) F(1) F(2) F(3) F(4) F(5) F(6) F(7) F(8) F(9) F(10) F(11) F(12)
#define REP26(F) F(0) F(1) F(2) F(3) F(4) F(5) F(6) F(7) F(8) F(9) F(10) F(11) F(12) \
                 F(13) F(14) F(15) F(16) F(17) F(18) F(19) F(20) F(21) F(22) F(23) F(24) F(25)

// One wave per sample. Lane l<51 = LSTM1 row l (4 gates, f16-pair weights in
// 104 NAMED scalar VGPRs — no arrays: allocas were never promoted out of
// scratch in rounds 1-4, that was the whole 1.3 GB FETCH / 12% VALUBusy
// bottleneck). Lane 51 = LSTM2 through the identical matvec+nonlinearity,
// one step skewed. x-projection fused: every 64 steps, commit 13 prefetched
// float4 (issued 64 steps earlier) to LDS, each lane dots its own row.
__global__ __attribute__((amdgpu_flat_work_group_size(64, 64), amdgpu_waves_per_eu(1)))
void rnn_kernel(
    const float* __restrict__ x,
    const float* __restrict__ Wl, const float* __restrict__ bl,
    const float* __restrict__ Wih1, const float* __restrict__ Whh1,
    const float* __restrict__ bih1, const float* __restrict__ bhh1,
    const float* __restrict__ Wih2, const float* __restrict__ Whh2,
    const float* __restrict__ bih2, const float* __restrict__ bhh2,
    const float* __restrict__ Wa, const float* __restrict__ ba,
    float* __restrict__ out)
{
    const int n    = blockIdx.x;
    const int lane = threadIdx.x;
    float* optr = out + (size_t)n * T_STEPS;
    const float4* x4 = (const float4*)x;
    const int sbase = n * (T_STEPS * FEAT / 4);  // sample base in float4s

    __shared__ float tile[64 * FEAT];
    float4* t4 = (float4*)tile;

    // ---- named weight registers (no allocas!) ----
#define DECLW(j) int w0_##j, w1_##j, w2_##j, w3_##j;
    REP26(DECLW)
#define DECLS(j) int sh_##j;
    REP26(DECLS)
#define DECLP(i) float4 p_##i;
    REP13(DECLP)

    // ---- one-time weight load -> packed f16 pairs ----
    {
        const float *s0, *s1, *s2, *s3;
        float msk;
        if (lane < HID) {
            s0 = Whh1 + (0 * HID + lane) * HID;
            s1 = Whh1 + (1 * HID + lane) * HID;
            s2 = Whh1 + (2 * HID + lane) * HID;
            s3 = Whh1 + (3 * HID + lane) * HID;
            msk = 1.0f;
        } else {
            s0 = Wih2 + 0 * HID; s1 = Wih2 + 1 * HID;
            s2 = Wih2 + 2 * HID; s3 = Wih2 + 3 * HID;
            msk = (lane == HID) ? 1.0f : 0.0f;
        }
        const float m2 = (lane == HID) ? 1.0f : 0.0f;
        const float h2w0 = Whh2[0] * m2, h2w1 = Whh2[1] * m2;
        const float h2w2 = Whh2[2] * m2, h2w3 = Whh2[3] * m2;
#define LOADW(j) { \
        float lo0 = s0[2*(j)] * msk, lo1 = s1[2*(j)] * msk; \
        float lo2 = s2[2*(j)] * msk, lo3 = s3[2*(j)] * msk; \
        float hi0, hi1, hi2, hi3; \
        if (2*(j)+1 < HID) { \
            hi0 = s0[2*(j)+1] * msk; hi1 = s1[2*(j)+1] * msk; \
            hi2 = s2[2*(j)+1] * msk; hi3 = s3[2*(j)+1] * msk; \
        } else { hi0 = h2w0; hi1 = h2w1; hi2 = h2w2; hi3 = h2w3; } \
        w0_##j = packh2(lo0, hi0); w1_##j = packh2(lo1, hi1); \
        w2_##j = packh2(lo2, hi2); w3_##j = packh2(lo3, hi3); \
        asm("" : "+v"(w0_##j), "+v"(w1_##j), "+v"(w2_##j), "+v"(w3_##j)); }
        REP26(LOADW)
    }

    // per-lane x-weights and biases (fp32)
    float wx0 = 0.0f, wx1 = 0.0f, wx2 = 0.0f, wx3 = 0.0f;
    float b0 = 0.0f, b1 = 0.0f, b2 = 0.0f, b3 = 0.0f;
    if (lane < HID) {
        wx0 = Wih1[lane];           wx1 = Wih1[HID + lane];
        wx2 = Wih1[2 * HID + lane]; wx3 = Wih1[3 * HID + lane];
        b0 = bih1[lane] + bhh1[lane];
        b1 = bih1[HID + lane] + bhh1[HID + lane];
        b2 = bih1[2 * HID + lane] + bhh1[2 * HID + lane];
        b3 = bih1[3 * HID + lane] + bhh1[3 * HID + lane];
    } else if (lane == HID) {
        b0 = bih2[0] + bhh2[0]; b1 = bih2[1] + bhh2[1];
        b2 = bih2[2] + bhh2[2]; b3 = bih2[3] + bhh2[3];
    }
    const float wav = Wa[0], bav = ba[0];
    const float bl0 = bl[0];

#define INITS(j) sh_##j = 0;
    REP26(INITS)

    float c = 0.0f, h = 0.0f;

    // ---- fused x-projection machinery ----
#define PF(i) { int gi = pf_base + (i)*64 + lane; gi = gi < XTOT4 ? gi : (XTOT4 - 1); p_##i = x4[gi]; }
#define CW(i) { int li = (i)*64 + lane; if (li < ROWF4) t4[li] = p_##i; }
#define COMMIT_DOT(dst) { REP13(CW) \
        float dd_ = row_dot(&tile[lane * FEAT], Wl); \
        dst = fmaxf(dd_ + bl0, 0.0f); }

    float xa, xb;
    int pf_base;
    pf_base = sbase;             REP13(PF) COMMIT_DOT(xa)   // chunk 0
    pf_base = sbase + ROWF4;     REP13(PF) COMMIT_DOT(xb)   // chunk 1
    pf_base = sbase + 2 * ROWF4; REP13(PF)                  // chunk 2 in flight

#pragma unroll 1
    for (int t = 0; t <= T_STEPS; ++t) {
        if ((t & 63) == 0 && t > 0 && t < T_STEPS) {
            xa = xb;
            COMMIT_DOT(xb)                                  // chunk (t>>6)+1
            pf_base = sbase + ((t >> 6) + 2) * ROWF4;
            REP13(PF)                                       // chunk (t>>6)+2
        }
        float xt = rl(xa, t & 63);

        // ---- matvec: 4 gate rows/lane, 26 dot2 each (f32 accumulate) ----
        float a0 = fmaf(wx0, xt, b0);
        float a1 = fmaf(wx1, xt, b1);
        float a2 = fmaf(wx2, xt, b2);
        float a3 = fmaf(wx3, xt, b3);
#define DOT(j) a0 = dot2(w0_##j, sh_##j, a0); a1 = dot2(w1_##j, sh_##j, a1); \
               a2 = dot2(w2_##j, sh_##j, a2); a3 = dot2(w3_##j, sh_##j, a3);
        REP26(DOT)

        // ---- shared nonlinearity + state update (lane51 = LSTM2) ----
        float ig = sigmoidf_fast(a0);
        float fg = sigmoidf_fast(a1);
        float gg = tanhf_fast(a2);
        float og = sigmoidf_fast(a3);
        c = fmaf(fg, c, ig * gg);
        h = og * tanhf_fast(c);
        if (t == 0 && lane >= HID) { c = 0.0f; h = 0.0f; }  // LSTM2 zero init (skewed)

        float outv = fmaf(h, wav, bav);
        if (t > 0 && lane == HID) optr[t - 1] = outv;

        // ---- broadcast h as f16 pairs for next step (SGPRs) ----
        int hz = (int)(unsigned)__builtin_bit_cast(unsigned short, (_Float16)h);
#define BCAST(j) sh_##j = rli(hz, 2*(j)) | (rli(hz, 2*(j)+1) << 16);
        REP26(BCAST)
    }
}

extern "C" void kernel_launch(void* const* d_in, const int* in_sizes, int n_in,
                              void* d_out, int out_size, void* d_ws, size_t ws_size,
                              hipStream_t stream) {
    const float* x    = (const float*)d_in[0];
    const float* Wl   = (const float*)d_in[1];
    const float* bl   = (const float*)d_in[2];
    const float* Wih1 = (const float*)d_in[3];
    const float* Whh1 = (const float*)d_in[4];
    const float* bih1 = (const float*)d_in[5];
    const float* bhh1 = (const float*)d_in[6];
    const float* Wih2 = (const float*)d_in[7];
    const float* Whh2 = (const float*)d_in[8];
    const float* bih2 = (const float*)d_in[9];
    const float* bhh2 = (const float*)d_in[10];
    const float* Wa   = (const float*)d_in[11];
    const float* ba   = (const float*)d_in[12];
    float* out = (float*)d_out;

    rnn_kernel<<<NBATCH, 64, 0, stream>>>(x, Wl, bl, Wih1, Whh1, bih1, bhh1,
                                          Wih2, Whh2, bih2, bhh2, Wa, ba, out);
}

// Round 6
// 948.968 us; speedup vs baseline: 1.6480x; 1.6404x over previous
//
#include <hip/hip_runtime.h>

#define T_STEPS 2000
#define NBATCH  256
#define HID     51
#define FEAT    49
#define ROWF4   784                         // 64 rows * 49 floats / 4
#define XTOT4   (NBATCH * T_STEPS * FEAT / 4)
#define PSTRIDE 5                           // preact tile row stride (dwords), odd => conflict-free

typedef _Float16 v2h __attribute__((ext_vector_type(2)));

__device__ __forceinline__ float rl(float v, int lane) {
    return __int_as_float(__builtin_amdgcn_readlane(__float_as_int(v), lane));
}
__device__ __forceinline__ int rli(int v, int lane) {
    return __builtin_amdgcn_readlane(v, lane);
}
__device__ __forceinline__ float sigmoidf_fast(float x) {
    return __builtin_amdgcn_rcpf(1.0f + __builtin_amdgcn_exp2f(-1.4426950408889634f * x));
}
__device__ __forceinline__ float tanhf_fast(float x) {
    return 1.0f - 2.0f * __builtin_amdgcn_rcpf(1.0f + __builtin_amdgcn_exp2f(2.8853900817779268f * x));
}
__device__ __forceinline__ int packh2(float lo, float hi) {
    v2h p = (v2h){(_Float16)lo, (_Float16)hi};
    return __builtin_bit_cast(int, p);
}
__device__ __forceinline__ float dot2(int w, int h, float acc) {
    return __builtin_amdgcn_fdot2(__builtin_bit_cast(v2h, w),
                                  __builtin_bit_cast(v2h, h), acc, false);
}
__device__ __forceinline__ float row_dot(const float* row, const float* __restrict__ Wl) {
    float a0 = 0, a1 = 0, a2 = 0, a3 = 0, a4 = 0, a5 = 0, a6 = 0;
#pragma unroll
    for (int j = 0; j < FEAT; j += 7) {
        a0 = fmaf(row[j    ], Wl[j    ], a0);
        a1 = fmaf(row[j + 1], Wl[j + 1], a1);
        a2 = fmaf(row[j + 2], Wl[j + 2], a2);
        a3 = fmaf(row[j + 3], Wl[j + 3], a3);
        a4 = fmaf(row[j + 4], Wl[j + 4], a4);
        a5 = fmaf(row[j + 5], Wl[j + 5], a5);
        a6 = fmaf(row[j + 6], Wl[j + 6], a6);
    }
    return ((a0 + a1) + (a2 + a3)) + ((a4 + a5) + a6);
}

#define REP26(F) F(0) F(1) F(2) F(3) F(4) F(5) F(6) F(7) F(8) F(9) F(10) F(11) F(12) \
                 F(13) F(14) F(15) F(16) F(17) F(18) F(19) F(20) F(21) F(22) F(23) F(24) F(25)

// 4 waves per sample (one per gate). Per-lane weights: 26 packed-f16 ints —
// small enough that the allocator provably keeps them resident (rounds 1-5:
// 200-reg/lane designs always spilled; ~60 never did). Per-step: 26 dot2 per
// wave (4 SIMDs in parallel), gate exchange through a stride-5 LDS tile with
// ONE barrier + double buffer; every wave redundantly runs the nonlinearity
// for its lane's row, so no second barrier. h broadcast: f16 cvt + quad_perm
// DPP pair-pack + 26 readlanes. Outputs buffered in LDS, flushed as one
// coalesced store per 64 steps (keeps the per-step barrier's vmcnt(0) drain
// free of global-store latency). x-projection fused, prefetch spread over
// all 256 threads.
__global__ __attribute__((amdgpu_flat_work_group_size(256, 256), amdgpu_waves_per_eu(1)))
void rnn_kernel(
    const float* __restrict__ x,
    const float* __restrict__ Wl, const float* __restrict__ bl,
    const float* __restrict__ Wih1, const float* __restrict__ Whh1,
    const float* __restrict__ bih1, const float* __restrict__ bhh1,
    const float* __restrict__ Wih2, const float* __restrict__ Whh2,
    const float* __restrict__ bih2, const float* __restrict__ bhh2,
    const float* __restrict__ Wa, const float* __restrict__ ba,
    float* __restrict__ out)
{
    const int n    = blockIdx.x;
    const int tid  = threadIdx.x;
    const int wid  = tid >> 6;      // gate index
    const int lane = tid & 63;
    float* optr = out + (size_t)n * T_STEPS;
    const float4* x4 = (const float4*)x;
    const int sbase = n * (T_STEPS * FEAT / 4);

    __shared__ float xt_[64 * FEAT];            // 12544 B x-tile
    __shared__ float pt[2][64 * PSTRIDE];       // 2560 B preact exchange
    __shared__ float ob[64];                    // 256 B output buffer
    float4* t4 = (float4*)xt_;

    // ---- weights: 26 packed f16 pairs per lane (named scalars) ----
#define DECLW(j) int w_##j; int sh_##j;
    REP26(DECLW)
    {
        const float* srow;
        float msk;
        if (lane < HID) { srow = Whh1 + (wid * HID + lane) * HID; msk = 1.0f; }
        else            { srow = Wih2 + wid * HID; msk = (lane == HID) ? 1.0f : 0.0f; }
        const float wh2 = Whh2[wid] * ((lane == HID) ? 1.0f : 0.0f);
#define LOADW(j) { \
        float lo = srow[2*(j)] * msk; \
        float hi = (2*(j)+1 < HID) ? srow[2*(j)+1] * msk : wh2; \
        w_##j = packh2(lo, hi); \
        asm("" : "+v"(w_##j)); }
        REP26(LOADW)
    }

    float wx = 0.0f, b = 0.0f;
    if (lane < HID) {
        wx = Wih1[wid * HID + lane];
        b  = bih1[wid * HID + lane] + bhh1[wid * HID + lane];
    } else if (lane == HID) {
        b  = bih2[wid] + bhh2[wid];
    }
    const float wav = Wa[0], bav = ba[0];
    const float bl0 = bl[0];

#define INITS(j) sh_##j = 0;
    REP26(INITS)

    float c = 0.0f, h = 0.0f;

    // ---- x prefetch: 784 float4 per 64-step chunk spread over 256 threads ----
    float4 p0, p1, p2, p3;
#define PF(base) { \
        int g0_ = (base) + tid;       g0_ = g0_ < XTOT4 ? g0_ : (XTOT4 - 1); p0 = x4[g0_]; \
        int g1_ = (base) + 256 + tid; g1_ = g1_ < XTOT4 ? g1_ : (XTOT4 - 1); p1 = x4[g1_]; \
        int g2_ = (base) + 512 + tid; g2_ = g2_ < XTOT4 ? g2_ : (XTOT4 - 1); p2 = x4[g2_]; \
        if (tid < 16) { int g3_ = (base) + 768 + tid; g3_ = g3_ < XTOT4 ? g3_ : (XTOT4 - 1); p3 = x4[g3_]; } }
#define COMMIT { t4[tid] = p0; t4[tid + 256] = p1; t4[tid + 512] = p2; \
                 if (tid < 16) t4[tid + 768] = p3; }
#define ROWDOT(dst) { float d_ = row_dot(&xt_[lane * FEAT], Wl); \
                      dst = fmaxf(d_ + bl0, 0.0f); }

    float xa, xb;
    PF(sbase)              COMMIT  __syncthreads();  ROWDOT(xa)   // chunk 0
    PF(sbase + ROWF4)      __syncthreads();  COMMIT  __syncthreads();  ROWDOT(xb)  // chunk 1
    PF(sbase + 2 * ROWF4)                                         // chunk 2 in flight

    const int prow = lane * PSTRIDE;

#pragma unroll 1
    for (int t = 0; t <= T_STEPS; ++t) {
        if ((t & 63) == 0 && t > 0 && t < T_STEPS) {
            const int k = t >> 6;
            if (wid == 0) {                       // flush outputs (wave0-internal)
                int oi = 64 * (k - 1) - 1 + lane;
                float ov = ob[lane];
                if (oi >= 0) optr[oi] = ov;
            }
            xa = xb;
            COMMIT                                 // chunk k+1 -> x-tile
            __syncthreads();
            ROWDOT(xb)
            PF(sbase + (k + 2) * ROWF4)            // chunk k+2 in flight
        }
        float xt = rl(xa, t & 63);

        // ---- this wave's gate preact: 2 interleaved dot2 chains ----
        float aA = fmaf(wx, xt, b), aB = 0.0f;
#define DOT(j) { if ((j) & 1) aB = dot2(w_##j, sh_##j, aB); \
                 else         aA = dot2(w_##j, sh_##j, aA); }
        REP26(DOT)
        float a = aA + aB;

        // ---- exchange: write own gate, barrier, read all 4 ----
        float* ptw = pt[t & 1];
        ptw[prow + wid] = a;
        __syncthreads();
        float g0 = ptw[prow + 0];
        float g1 = ptw[prow + 1];
        float g2 = ptw[prow + 2];
        float g3 = ptw[prow + 3];

        // ---- nonlinearity (redundant per wave; lane51 = LSTM2) ----
        float ig = sigmoidf_fast(g0);
        float fg = sigmoidf_fast(g1);
        float gg = tanhf_fast(g2);
        float og = sigmoidf_fast(g3);
        c = fmaf(fg, c, ig * gg);
        h = og * tanhf_fast(c);
        if (t == 0 && lane >= HID) { c = 0.0f; h = 0.0f; }   // LSTM2 zero init (skew)

        if (wid == 0 && lane == HID && t > 0)                 // buffer output in LDS
            ob[t & 63] = fmaf(h, wav, bav);

        // ---- h broadcast: f16 cvt + quad_perm neighbor + 26 readlanes ----
        int hz = (int)(unsigned)__builtin_bit_cast(unsigned short, (_Float16)h);
        int nb = __builtin_amdgcn_mov_dpp(hz, 0xB1, 0xF, 0xF, true);  // lane r <-> r^1
        int pair = hz | (nb << 16);          // even lane r: h[r] | h[r+1]<<16
#define BCAST(j) sh_##j = rli(pair, 2 * (j));
        REP26(BCAST)
    }

    // final output flush: out idx 1983..1999 live in slots 0..16
    if (wid == 0 && lane <= 16) optr[1983 + lane] = ob[lane];
}

extern "C" void kernel_launch(void* const* d_in, const int* in_sizes, int n_in,
                              void* d_out, int out_size, void* d_ws, size_t ws_size,
                              hipStream_t stream) {
    const float* x    = (const float*)d_in[0];
    const float* Wl   = (const float*)d_in[1];
    const float* bl   = (const float*)d_in[2];
    const float* Wih1 = (const float*)d_in[3];
    const float* Whh1 = (const float*)d_in[4];
    const float* bih1 = (const float*)d_in[5];
    const float* bhh1 = (const float*)d_in[6];
    const float* Wih2 = (const float*)d_in[7];
    const float* Whh2 = (const float*)d_in[8];
    const float* bih2 = (const float*)d_in[9];
    const float* bhh2 = (const float*)d_in[10];
    const float* Wa   = (const float*)d_in[11];
    const float* ba   = (const float*)d_in[12];
    float* out = (float*)d_out;

    rnn_kernel<<<NBATCH, 256, 0, stream>>>(x, Wl, bl, Wih1, Whh1, bih1, bhh1,
                                           Wih2, Whh2, bih2, bhh2, Wa, ba, out);
}

// Round 7
// 874.287 us; speedup vs baseline: 1.7888x; 1.0854x over previous
//
#include <hip/hip_runtime.h>

#define T_STEPS 2000
#define NBATCH  256
#define HID     51
#define FEAT    49
#define ROWF4   784                         // 64 rows * 49 floats / 4
#define XTOT4   (NBATCH * T_STEPS * FEAT / 4)
#define PSTRIDE 5                           // preact tile row stride (dwords), odd => conflict-free

typedef _Float16 v2h __attribute__((ext_vector_type(2)));

__device__ __forceinline__ float rl(float v, int lane) {
    return __int_as_float(__builtin_amdgcn_readlane(__float_as_int(v), lane));
}
__device__ __forceinline__ int rli(int v, int lane) {
    return __builtin_amdgcn_readlane(v, lane);
}
__device__ __forceinline__ float sigmoidf_fast(float x) {
    return __builtin_amdgcn_rcpf(1.0f + __builtin_amdgcn_exp2f(-1.4426950408889634f * x));
}
__device__ __forceinline__ float tanhf_fast(float x) {
    return 1.0f - 2.0f * __builtin_amdgcn_rcpf(1.0f + __builtin_amdgcn_exp2f(2.8853900817779268f * x));
}
__device__ __forceinline__ int packh2(float lo, float hi) {
    v2h p = (v2h){(_Float16)lo, (_Float16)hi};
    return __builtin_bit_cast(int, p);
}
__device__ __forceinline__ float dot2(int w, int h, float acc) {
    return __builtin_amdgcn_fdot2(__builtin_bit_cast(v2h, w),
                                  __builtin_bit_cast(v2h, h), acc, false);
}
// LDS-only barrier: skips the vmcnt(0)/expcnt(0) drain __syncthreads emits.
// Every sync point in this kernel orders LDS traffic only (prefetch-load
// consumption is guarded by compiler-inserted vmcnt waits at the ds_write;
// global output stores have no in-kernel readers).
__device__ __forceinline__ void bar_lds() {
    asm volatile("s_waitcnt lgkmcnt(0)" ::: "memory");
    __builtin_amdgcn_s_barrier();
    asm volatile("" ::: "memory");
}
__device__ __forceinline__ float row_dot(const float* row, const float* __restrict__ Wl) {
    float a0 = 0, a1 = 0, a2 = 0, a3 = 0, a4 = 0, a5 = 0, a6 = 0;
#pragma unroll
    for (int j = 0; j < FEAT; j += 7) {
        a0 = fmaf(row[j    ], Wl[j    ], a0);
        a1 = fmaf(row[j + 1], Wl[j + 1], a1);
        a2 = fmaf(row[j + 2], Wl[j + 2], a2);
        a3 = fmaf(row[j + 3], Wl[j + 3], a3);
        a4 = fmaf(row[j + 4], Wl[j + 4], a4);
        a5 = fmaf(row[j + 5], Wl[j + 5], a5);
        a6 = fmaf(row[j + 6], Wl[j + 6], a6);
    }
    return ((a0 + a1) + (a2 + a3)) + ((a4 + a5) + a6);
}

#define REP26(F) F(0) F(1) F(2) F(3) F(4) F(5) F(6) F(7) F(8) F(9) F(10) F(11) F(12) \
                 F(13) F(14) F(15) F(16) F(17) F(18) F(19) F(20) F(21) F(22) F(23) F(24) F(25)

// 4 waves per sample (one per gate). Per-lane weights: 26 packed-f16 ints.
// NEW vs round 6: (a) each wave applies its OWN gate's activation before the
// exchange (sigma for waves 0/1/3, tanh for wave 2) so the post-barrier
// serial chain is just c=fma(f,c,i*g); h=o*tanh(c) — 2 transcendentals
// instead of 8 on the critical path; (b) all barriers are lgkmcnt-only
// (bar_lds), never draining vmcnt/expcnt.
__global__ __attribute__((amdgpu_flat_work_group_size(256, 256), amdgpu_waves_per_eu(1)))
void rnn_kernel(
    const float* __restrict__ x,
    const float* __restrict__ Wl, const float* __restrict__ bl,
    const float* __restrict__ Wih1, const float* __restrict__ Whh1,
    const float* __restrict__ bih1, const float* __restrict__ bhh1,
    const float* __restrict__ Wih2, const float* __restrict__ Whh2,
    const float* __restrict__ bih2, const float* __restrict__ bhh2,
    const float* __restrict__ Wa, const float* __restrict__ ba,
    float* __restrict__ out)
{
    const int n    = blockIdx.x;
    const int tid  = threadIdx.x;
    const int wid  = tid >> 6;      // gate index
    const int lane = tid & 63;
    float* optr = out + (size_t)n * T_STEPS;
    const float4* x4 = (const float4*)x;
    const int sbase = n * (T_STEPS * FEAT / 4);

    __shared__ float xt_[64 * FEAT];            // 12544 B x-tile
    __shared__ float pt[2][64 * PSTRIDE];       // 2560 B activated-gate exchange
    __shared__ float ob[64];                    // 256 B output buffer
    float4* t4 = (float4*)xt_;

    // ---- weights: 26 packed f16 pairs per lane (named scalars) ----
#define DECLW(j) int w_##j; int sh_##j;
    REP26(DECLW)
    {
        const float* srow;
        float msk;
        if (lane < HID) { srow = Whh1 + (wid * HID + lane) * HID; msk = 1.0f; }
        else            { srow = Wih2 + wid * HID; msk = (lane == HID) ? 1.0f : 0.0f; }
        const float wh2 = Whh2[wid] * ((lane == HID) ? 1.0f : 0.0f);
#define LOADW(j) { \
        float lo = srow[2*(j)] * msk; \
        float hi = (2*(j)+1 < HID) ? srow[2*(j)+1] * msk : wh2; \
        w_##j = packh2(lo, hi); \
        asm("" : "+v"(w_##j)); }
        REP26(LOADW)
    }

    float wx = 0.0f, b = 0.0f;
    if (lane < HID) {
        wx = Wih1[wid * HID + lane];
        b  = bih1[wid * HID + lane] + bhh1[wid * HID + lane];
    } else if (lane == HID) {
        b  = bih2[wid] + bhh2[wid];
    }
    const float wav = Wa[0], bav = ba[0];
    const float bl0 = bl[0];

#define INITS(j) sh_##j = 0;
    REP26(INITS)

    float c = 0.0f, h = 0.0f;

    // ---- x prefetch: 784 float4 per 64-step chunk spread over 256 threads ----
    float4 p0, p1, p2, p3;
#define PF(base) { \
        int g0_ = (base) + tid;       g0_ = g0_ < XTOT4 ? g0_ : (XTOT4 - 1); p0 = x4[g0_]; \
        int g1_ = (base) + 256 + tid; g1_ = g1_ < XTOT4 ? g1_ : (XTOT4 - 1); p1 = x4[g1_]; \
        int g2_ = (base) + 512 + tid; g2_ = g2_ < XTOT4 ? g2_ : (XTOT4 - 1); p2 = x4[g2_]; \
        if (tid < 16) { int g3_ = (base) + 768 + tid; g3_ = g3_ < XTOT4 ? g3_ : (XTOT4 - 1); p3 = x4[g3_]; } }
#define COMMIT { t4[tid] = p0; t4[tid + 256] = p1; t4[tid + 512] = p2; \
                 if (tid < 16) t4[tid + 768] = p3; }
#define ROWDOT(dst) { float d_ = row_dot(&xt_[lane * FEAT], Wl); \
                      dst = fmaxf(d_ + bl0, 0.0f); }

    float xa, xb;
    PF(sbase)              COMMIT  bar_lds();  ROWDOT(xa)                // chunk 0
    PF(sbase + ROWF4)      bar_lds();  COMMIT  bar_lds();  ROWDOT(xb)    // chunk 1
    PF(sbase + 2 * ROWF4)                                                // chunk 2 in flight

    const int prow = lane * PSTRIDE;

#pragma unroll 1
    for (int t = 0; t <= T_STEPS; ++t) {
        if ((t & 63) == 0 && t > 0 && t < T_STEPS) {
            const int k = t >> 6;
            if (wid == 0) {                       // flush outputs (wave0-internal)
                int oi = 64 * (k - 1) - 1 + lane;
                float ov = ob[lane];
                if (oi >= 0) optr[oi] = ov;
            }
            xa = xb;
            COMMIT                                 // chunk k+1 -> x-tile
            bar_lds();
            ROWDOT(xb)
            PF(sbase + (k + 2) * ROWF4)            // chunk k+2 in flight
        }
        float xt = rl(xa, t & 63);

        // ---- this wave's gate preact: 2 interleaved dot2 chains ----
        float aA = fmaf(wx, xt, b), aB = 0.0f;
#define DOT(j) { if ((j) & 1) aB = dot2(w_##j, sh_##j, aB); \
                 else         aA = dot2(w_##j, sh_##j, aA); }
        REP26(DOT)
        float a = aA + aB;

        // ---- own-gate activation BEFORE exchange (wave-uniform branch) ----
        float act = (wid == 2) ? tanhf_fast(a) : sigmoidf_fast(a);

        // ---- exchange activated gates: write own, barrier, read all 4 ----
        float* ptw = pt[t & 1];
        ptw[prow + wid] = act;
        bar_lds();
        float ig = ptw[prow + 0];
        float fg = ptw[prow + 1];
        float gg = ptw[prow + 2];
        float og = ptw[prow + 3];

        // ---- short state update (redundant per wave; lane51 = LSTM2) ----
        c = fmaf(fg, c, ig * gg);
        h = og * tanhf_fast(c);
        if (t == 0 && lane >= HID) { c = 0.0f; h = 0.0f; }   // LSTM2 zero init (skew)

        if (wid == 0 && lane == HID && t > 0)                 // buffer output in LDS
            ob[t & 63] = fmaf(h, wav, bav);

        // ---- h broadcast: f16 cvt + quad_perm neighbor + 26 readlanes ----
        int hz = (int)(unsigned)__builtin_bit_cast(unsigned short, (_Float16)h);
        int nb = __builtin_amdgcn_mov_dpp(hz, 0xB1, 0xF, 0xF, true);  // lane r <-> r^1
        int pair = hz | (nb << 16);          // even lane r: h[r] | h[r+1]<<16
#define BCAST(j) sh_##j = rli(pair, 2 * (j));
        REP26(BCAST)
    }

    // final output flush: out idx 1983..1999 live in slots 0..16
    if (wid == 0 && lane <= 16) optr[1983 + lane] = ob[lane];
}

extern "C" void kernel_launch(void* const* d_in, const int* in_sizes, int n_in,
                              void* d_out, int out_size, void* d_ws, size_t ws_size,
                              hipStream_t stream) {
    const float* x    = (const float*)d_in[0];
    const float* Wl   = (const float*)d_in[1];
    const float* bl   = (const float*)d_in[2];
    const float* Wih1 = (const float*)d_in[3];
    const float* Whh1 = (const float*)d_in[4];
    const float* bih1 = (const float*)d_in[5];
    const float* bhh1 = (const float*)d_in[6];
    const float* Wih2 = (const float*)d_in[7];
    const float* Whh2 = (const float*)d_in[8];
    const float* bih2 = (const float*)d_in[9];
    const float* bhh2 = (const float*)d_in[10];
    const float* Wa   = (const float*)d_in[11];
    const float* ba   = (const float*)d_in[12];
    float* out = (float*)d_out;

    rnn_kernel<<<NBATCH, 256, 0, stream>>>(x, Wl, bl, Wih1, Whh1, bih1, bhh1,
                                           Wih2, Whh2, bih2, bhh2, Wa, ba, out);
}